// Round 1
// baseline (248.287 us; speedup 1.0000x reference)
//
#include <hip/hip_runtime.h>
#include <math.h>

#define OCT_EPS 1e-8f

// <2 x float> ext vector: each lane processes TWO octonions so the fp32
// math maps to gfx950 packed ops (v_pk_fma_f32 / v_pk_mul_f32).
typedef float v2f __attribute__((ext_vector_type(2)));

static __device__ __forceinline__ v2f splat(float x) { v2f r; r.x = x; r.y = x; return r; }
static __device__ __forceinline__ v2f fma2(v2f a, v2f b, v2f c) {
    return __builtin_elementwise_fma(a, b, c);
}

// Constant-folded A&S 7.1.26 gelu, worked in x'' = pre * C space where
// C = (1/sqrt(2)) * sqrt(log2 e).  Then:
//   exp(-z^2)        = exp2(-(x'')^2)                 (log2e prefolded)
//   1 + 0.3275911*z  = 1 + K1*|x''|,  K1 = 0.3275911 / sqrt(log2 e)
//   gelu(x)          = KF * (x'' + |x''| * (1 - p*t*e)),  KF = 0.5 / C
// Identical math to the previous kernel's fast_erf path up to ~1 ulp
// constant rounding — no approximation change.

__global__ __launch_bounds__(256) void g2_ffn_kernel(
    const float* __restrict__ o,
    const float* __restrict__ W1,   // (32,2) row-major
    const float* __restrict__ b1,   // (32,)
    const float* __restrict__ W2,   // (3,32) row-major
    const float* __restrict__ b2,   // (3,)
    const float* __restrict__ alpha_p,
    float* __restrict__ out,
    int half)                        // n_oct / 2
{
    int i = blockIdx.x * blockDim.x + threadIdx.x;
    if (i >= half) return;
    size_t i0 = (size_t)i;
    size_t i1 = i0 + (size_t)half;   // second octonion: disjoint contiguous half

    const float4* ip = (const float4*)o;
    float4 lo0 = ip[2 * i0];
    float4 hi0 = ip[2 * i0 + 1];
    float4 lo1 = ip[2 * i1];
    float4 hi1 = ip[2 * i1 + 1];

    // Pair the two octonions component-wise.
    v2f wv = { lo0.x, lo1.x };
    v2f c1 = { lo0.y, lo1.y }, c2 = { lo0.z, lo1.z }, c3 = { lo0.w, lo1.w };
    v2f c4 = { hi0.x, hi1.x }, c5 = { hi0.y, hi1.y }, c6 = { hi0.z, hi1.z }, c7 = { hi0.w, hi1.w };

    v2f n2 = c1 * c1;
    n2 = fma2(c2, c2, n2);
    n2 = fma2(c3, c3, n2);
    n2 = fma2(c4, c4, n2);
    n2 = fma2(c5, c5, n2);
    n2 = fma2(c6, c6, n2);
    n2 = fma2(c7, c7, n2);
    v2f nv = { __builtin_amdgcn_sqrtf(n2.x), __builtin_amdgcn_sqrtf(n2.y) };
    v2f sv = fma2(wv, wv, n2);       // |o|^2

    const float C_  = 0.84932185f;   // (1/sqrt(2)) * sqrt(log2 e)
    const float K1_ = 0.2727374f;    // 0.3275911 / sqrt(log2 e)
    const float KF_ = 0.5887050f;    // 0.5 / C_

    v2f accA = splat(0.0f), accB = splat(0.0f), accC = splat(0.0f);
#pragma unroll
    for (int j = 0; j < 32; ++j) {
        v2f pre = fma2(splat(W1[2 * j]), wv,
                  fma2(splat(W1[2 * j + 1]), nv, splat(b1[j])));
        v2f x2 = pre * splat(C_);
        v2f z2 = x2 * x2;
        v2f e  = { exp2f(-z2.x), exp2f(-z2.y) };              // v_exp_f32
        v2f ax = { __builtin_fabsf(x2.x), __builtin_fabsf(x2.y) };
        v2f den = fma2(splat(K1_), ax, splat(1.0f));
        v2f t  = { __builtin_amdgcn_rcpf(den.x), __builtin_amdgcn_rcpf(den.y) };
        v2f p  = fma2(splat(1.061405429f), t, splat(-1.453152027f));
        p = fma2(p, t, splat(1.421413741f));
        p = fma2(p, t, splat(-0.284496736f));
        p = fma2(p, t, splat(0.254829592f));
        v2f pt = p * t;
        v2f m  = fma2(-pt, e, splat(1.0f));                   // erf(|z|)
        v2f g  = fma2(ax, m, x2);                             // x'' + |x''|*erf
        accA = fma2(splat(W2[j]),      g, accA);
        accB = fma2(splat(W2[32 + j]), g, accB);
        accC = fma2(splat(W2[64 + j]), g, accC);
    }

    // back-scale 0.5/C folded here (3 FMAs total instead of per-j)
    v2f av = fma2(splat(KF_), accA, splat(b2[0]));
    v2f bv = fma2(splat(KF_), accB, splat(b2[1]));
    v2f cv = fma2(splat(KF_), accC, splat(b2[2]));

    // upd = alpha_c * o + beta_c * e0 (octonion algebra collapsed)
    v2f q       = fma2(splat(4.0f) * wv, wv, -sv);            // 4w^2 - s
    v2f alpha_c = fma2(cv, q, fma2(bv + bv, wv, av));
    v2f beta_c  = -(sv * fma2(cv + cv, wv, bv));

    v2f ab = alpha_c * beta_c;
    v2f t2 = fma2(alpha_c * alpha_c, sv, fma2(ab + ab, wv, beta_c * beta_c));
    v2f nrm = { __builtin_amdgcn_sqrtf(t2.x), __builtin_amdgcn_sqrtf(t2.y) };
    v2f inv = { __builtin_amdgcn_rcpf(fmaxf(nrm.x, OCT_EPS)),
                __builtin_amdgcn_rcpf(fmaxf(nrm.y, OCT_EPS)) };

    float alpha_in = alpha_p[0];
    float lam = 1.0f / (1.0f + __expf(-alpha_in));
    float oml = 1.0f - lam;

    v2f la = splat(lam) * (alpha_c * inv);
    v2f lb = splat(lam) * (beta_c * inv);
    v2f sc = splat(oml) + la;        // (1-lam) + lam*alpha_c/|upd|

    v2f rw = fma2(sc, wv, lb);       // component 0 gets the beta_c*e0 term
    v2f r1 = sc * c1, r2 = sc * c2, r3 = sc * c3;
    v2f r4 = sc * c4, r5 = sc * c5, r6 = sc * c6, r7 = sc * c7;

    float4* op = (float4*)out;
    float4 a0 = { rw.x, r1.x, r2.x, r3.x };
    float4 a1 = { r4.x, r5.x, r6.x, r7.x };
    float4 b0 = { rw.y, r1.y, r2.y, r3.y };
    float4 b1o = { r4.y, r5.y, r6.y, r7.y };
    op[2 * i0]     = a0;
    op[2 * i0 + 1] = a1;
    op[2 * i1]     = b0;
    op[2 * i1 + 1] = b1o;
}

extern "C" void kernel_launch(void* const* d_in, const int* in_sizes, int n_in,
                              void* d_out, int out_size, void* d_ws, size_t ws_size,
                              hipStream_t stream) {
    const float* o     = (const float*)d_in[0];
    const float* W1    = (const float*)d_in[1];
    const float* b1    = (const float*)d_in[2];
    const float* W2    = (const float*)d_in[3];
    const float* b2    = (const float*)d_in[4];
    const float* alpha = (const float*)d_in[5];
    float* out = (float*)d_out;

    int n_oct = in_sizes[0] / 8;
    int half = n_oct >> 1;           // fixed shape: 16*4096*64 = 4194304, even
    int block = 256;
    int grid = (half + block - 1) / block;
    g2_ffn_kernel<<<grid, block, 0, stream>>>(o, W1, b1, W2, b2, alpha, out, half);
}

// Round 2
// 247.829 us; speedup vs baseline: 1.0019x; 1.0019x over previous
//
#include <hip/hip_runtime.h>
#include <math.h>

// Constant-folded A&S 7.1.26 gelu in x = pre*C space, C = sqrt(log2(e)/2):
//   exp(-z^2) = exp2(-x^2), den = 1 + K1*|x| (K1 = 0.3275911/sqrt(log2 e)),
//   gelu(pre) = KF * (x + |x|*erf(|x|)),  KF = 0.5/C  (folded into epilogue).
// Same constants as the passing round-1 kernel — no approximation change.

__global__ __launch_bounds__(256) void g2_ffn_kernel(
    const float* __restrict__ o,
    const float* __restrict__ W1,   // (32,2) row-major
    const float* __restrict__ b1,   // (32,)
    const float* __restrict__ W2,   // (3,32) row-major
    const float* __restrict__ b2,   // (3,)
    const float* __restrict__ alpha_p,
    float* __restrict__ out,
    int half)                        // n_oct / 2
{
    int i = blockIdx.x * blockDim.x + threadIdx.x;
    if (i >= half) return;
    size_t i0 = (size_t)i;
    size_t i1 = i0 + (size_t)half;   // two disjoint contiguous streams, both coalesced

    const float4* ip = (const float4*)o;
    float4 A0 = ip[2 * i0], A1 = ip[2 * i0 + 1];   // octonion 0
    float4 B0 = ip[2 * i1], B1 = ip[2 * i1 + 1];   // octonion 1

    // ---- invariants per octonion: w, n = |imag|, s = |o|^2 ----
    float wa = A0.x;
    float na2 = A0.y * A0.y;
    na2 = fmaf(A0.z, A0.z, na2);  na2 = fmaf(A0.w, A0.w, na2);
    na2 = fmaf(A1.x, A1.x, na2);  na2 = fmaf(A1.y, A1.y, na2);
    na2 = fmaf(A1.z, A1.z, na2);  na2 = fmaf(A1.w, A1.w, na2);
    float nna = __builtin_amdgcn_sqrtf(na2);
    float sa  = fmaf(wa, wa, na2);

    float wb = B0.x;
    float nb2 = B0.y * B0.y;
    nb2 = fmaf(B0.z, B0.z, nb2);  nb2 = fmaf(B0.w, B0.w, nb2);
    nb2 = fmaf(B1.x, B1.x, nb2);  nb2 = fmaf(B1.y, B1.y, nb2);
    nb2 = fmaf(B1.z, B1.z, nb2);  nb2 = fmaf(B1.w, B1.w, nb2);
    float nnb = __builtin_amdgcn_sqrtf(nb2);
    float sb  = fmaf(wb, wb, nb2);

    const float C_  = 0.84932180f;   // sqrt(log2(e)/2)
    const float K1_ = 0.2727375f;    // 0.3275911 / sqrt(log2 e)
    const float KF_ = 0.5887050f;    // 0.5 / C_

    float aA = 0.0f, aB = 0.0f, aC = 0.0f;   // stream a accumulators
    float bA = 0.0f, bB = 0.0f, bC = 0.0f;   // stream b accumulators

#pragma unroll
    for (int j = 0; j < 32; ++j) {
        // uniform weights: one s_load set serves both streams (128 oct/wave)
        float wr  = W1[2 * j];
        float wn  = W1[2 * j + 1];
        float bj  = b1[j];
        float w2a = W2[j];
        float w2b = W2[32 + j];
        float w2c = W2[64 + j];

        float xa = C_ * fmaf(wr, wa, fmaf(wn, nna, bj));
        float xb = C_ * fmaf(wr, wb, fmaf(wn, nnb, bj));

        float ea = __builtin_amdgcn_exp2f(-(xa * xa));   // neg folds into v_exp src mod
        float eb = __builtin_amdgcn_exp2f(-(xb * xb));

        float ta = __builtin_amdgcn_rcpf(fmaf(K1_, fabsf(xa), 1.0f)); // |x| = free mod
        float tb = __builtin_amdgcn_rcpf(fmaf(K1_, fabsf(xb), 1.0f));

        float pa = fmaf(1.061405429f, ta, -1.453152027f);
        float pb = fmaf(1.061405429f, tb, -1.453152027f);
        pa = fmaf(pa, ta, 1.421413741f);   pb = fmaf(pb, tb, 1.421413741f);
        pa = fmaf(pa, ta, -0.284496736f);  pb = fmaf(pb, tb, -0.284496736f);
        pa = fmaf(pa, ta, 0.254829592f);   pb = fmaf(pb, tb, 0.254829592f);

        float ga = fmaf(fabsf(xa), fmaf(-(pa * ta), ea, 1.0f), xa); // x + |x|*erf(|x|)
        float gb = fmaf(fabsf(xb), fmaf(-(pb * tb), eb, 1.0f), xb);

        aA = fmaf(w2a, ga, aA);   bA = fmaf(w2a, gb, bA);
        aB = fmaf(w2b, ga, aB);   bB = fmaf(w2b, gb, bB);
        aC = fmaf(w2c, ga, aC);   bC = fmaf(w2c, gb, bC);
    }

    // fold KF (gelu back-scale) into the b2 addition — 3 fma per stream
    float avA = fmaf(KF_, aA, b2[0]);
    float bvA = fmaf(KF_, aB, b2[1]);
    float cvA = fmaf(KF_, aC, b2[2]);
    float avB = fmaf(KF_, bA, b2[0]);
    float bvB = fmaf(KF_, bB, b2[1]);
    float cvB = fmaf(KF_, bC, b2[2]);

    float alpha_in = alpha_p[0];
    float lam = __builtin_amdgcn_rcpf(
        1.0f + __builtin_amdgcn_exp2f(-alpha_in * 1.44269504f));
    float oml = 1.0f - lam;

    // ---- epilogue stream a ----
    float qa  = fmaf(4.0f * wa, wa, -sa);
    float ala = fmaf(cvA, qa, fmaf(bvA + bvA, wa, avA));
    float bea = -(sa * fmaf(cvA + cvA, wa, bvA));
    float t2a = fmaf(ala * bea, wa + wa, fmaf(ala * ala, sa, bea * bea));
    // rsq(max(t2,1e-16)) == 1/max(sqrt(t2),1e-8) exactly (monotone); one trans
    float inva = __builtin_amdgcn_rsqf(fmaxf(t2a, 1e-16f));
    float laa = lam * ala * inva;
    float lba = lam * bea * inva;
    float sca = oml + laa;

    float4 ra0, ra1;
    ra0.x = fmaf(sca, A0.x, lba);
    ra0.y = sca * A0.y;  ra0.z = sca * A0.z;  ra0.w = sca * A0.w;
    ra1.x = sca * A1.x;  ra1.y = sca * A1.y;  ra1.z = sca * A1.z;  ra1.w = sca * A1.w;

    // ---- epilogue stream b ----
    float qb  = fmaf(4.0f * wb, wb, -sb);
    float alb = fmaf(cvB, qb, fmaf(bvB + bvB, wb, avB));
    float beb = -(sb * fmaf(cvB + cvB, wb, bvB));
    float t2b = fmaf(alb * beb, wb + wb, fmaf(alb * alb, sb, beb * beb));
    float invb = __builtin_amdgcn_rsqf(fmaxf(t2b, 1e-16f));
    float lab = lam * alb * invb;
    float lbb = lam * beb * invb;
    float scb = oml + lab;

    float4 rb0, rb1;
    rb0.x = fmaf(scb, B0.x, lbb);
    rb0.y = scb * B0.y;  rb0.z = scb * B0.z;  rb0.w = scb * B0.w;
    rb1.x = scb * B1.x;  rb1.y = scb * B1.y;  rb1.z = scb * B1.z;  rb1.w = scb * B1.w;

    float4* op = (float4*)out;
    op[2 * i0]     = ra0;
    op[2 * i0 + 1] = ra1;
    op[2 * i1]     = rb0;
    op[2 * i1 + 1] = rb1;
}

extern "C" void kernel_launch(void* const* d_in, const int* in_sizes, int n_in,
                              void* d_out, int out_size, void* d_ws, size_t ws_size,
                              hipStream_t stream) {
    const float* o     = (const float*)d_in[0];
    const float* W1    = (const float*)d_in[1];
    const float* b1    = (const float*)d_in[2];
    const float* W2    = (const float*)d_in[3];
    const float* b2    = (const float*)d_in[4];
    const float* alpha = (const float*)d_in[5];
    float* out = (float*)d_out;

    int n_oct = in_sizes[0] / 8;
    int half = n_oct >> 1;           // fixed shape: 16*4096*64 = 4194304, even
    int block = 256;
    int grid = (half + block - 1) / block;
    g2_ffn_kernel<<<grid, block, 0, stream>>>(o, W1, b1, W2, b2, alpha, out, half);
}

// Round 3
// 245.967 us; speedup vs baseline: 1.0094x; 1.0076x over previous
//
#include <hip/hip_runtime.h>
#include <math.h>

// ---- gelu LUT parameters: 256 cubic intervals over [-6.4, 6.4], h = 0.05 ----
#define NTAB     256
#define TAB_LO   -6.4f
#define TAB_H    0.05f
#define TAB_INVH 20.0f
#define TAB_BIAS 128.0f          // -TAB_LO * TAB_INVH

// A&S 7.1.26 erf (|err| <= 1.5e-7) — used ONLY at table build time, so the
// gelu error profile matches the previously passing kernels + <=3e-8 interp.
__device__ __forceinline__ float fast_erf(float x) {
    float z = fabsf(x);
    float t = __builtin_amdgcn_rcpf(fmaf(0.3275911f, z, 1.0f));
    float p = fmaf(1.061405429f, t, -1.453152027f);
    p = fmaf(p, t, 1.421413741f);
    p = fmaf(p, t, -0.284496736f);
    p = fmaf(p, t, 0.254829592f);
    p = p * t;
    float e = __builtin_amdgcn_exp2f(-(z * z) * 1.44269504f);
    float r = fmaf(-p, e, 1.0f);
    return copysignf(r, x);
}

__global__ __launch_bounds__(256) void g2_ffn_kernel(
    const float* __restrict__ o,
    const float* __restrict__ W1,   // (32,2) row-major
    const float* __restrict__ b1,   // (32,)
    const float* __restrict__ W2,   // (3,32) row-major
    const float* __restrict__ b2,   // (3,)
    const float* __restrict__ alpha_p,
    float* __restrict__ out,
    int half)                        // n_oct / 2
{
    __shared__ float4 tab[NTAB];     // 4 KB: per-interval cubic coeffs in frac-space

    int tid = threadIdx.x;

    // ---- build table: thread t owns interval t (block size == NTAB) ----
    {
        float m0 = fmaf((float)tid, TAB_H, TAB_LO);
        float m1 = m0 + TAB_H;
        // gelu(x) = x*Phi(x);  gelu'(x) = Phi(x) + x*phi(x)
        float Phi0 = 0.5f * (1.0f + fast_erf(m0 * 0.70710678f));
        float Phi1 = 0.5f * (1.0f + fast_erf(m1 * 0.70710678f));
        float phi0 = 0.39894228f * __builtin_amdgcn_exp2f(-(m0 * m0) * 0.72134752f);
        float phi1 = 0.39894228f * __builtin_amdgcn_exp2f(-(m1 * m1) * 0.72134752f);
        float g0 = m0 * Phi0;
        float g1 = m1 * Phi1;
        float d0 = TAB_H * fmaf(m0, phi0, Phi0);   // dg/dfrac at 0
        float d1 = TAB_H * fmaf(m1, phi1, Phi1);   // dg/dfrac at 1
        float4 c;
        c.x = g0;                                   // c0
        c.y = d0;                                   // c1
        c.z = 3.0f * (g1 - g0) - 2.0f * d0 - d1;    // c2
        c.w = 2.0f * (g0 - g1) + d0 + d1;           // c3
        tab[tid] = c;
    }
    __syncthreads();

    int i = blockIdx.x * blockDim.x + tid;
    if (i >= half) return;
    size_t i0 = (size_t)i;
    size_t i1 = i0 + (size_t)half;   // two disjoint contiguous streams, coalesced

    const float4* ip = (const float4*)o;
    float4 A0 = ip[2 * i0], A1 = ip[2 * i0 + 1];   // octonion a
    float4 B0 = ip[2 * i1], B1 = ip[2 * i1 + 1];   // octonion b

    // ---- invariants: w, n = |imag|, s = |o|^2 ----
    float wa = A0.x;
    float na2 = A0.y * A0.y;
    na2 = fmaf(A0.z, A0.z, na2);  na2 = fmaf(A0.w, A0.w, na2);
    na2 = fmaf(A1.x, A1.x, na2);  na2 = fmaf(A1.y, A1.y, na2);
    na2 = fmaf(A1.z, A1.z, na2);  na2 = fmaf(A1.w, A1.w, na2);
    float nna = __builtin_amdgcn_sqrtf(na2);
    float sa  = fmaf(wa, wa, na2);

    float wb = B0.x;
    float nb2 = B0.y * B0.y;
    nb2 = fmaf(B0.z, B0.z, nb2);  nb2 = fmaf(B0.w, B0.w, nb2);
    nb2 = fmaf(B1.x, B1.x, nb2);  nb2 = fmaf(B1.y, B1.y, nb2);
    nb2 = fmaf(B1.z, B1.z, nb2);  nb2 = fmaf(B1.w, B1.w, nb2);
    float nnb = __builtin_amdgcn_sqrtf(nb2);
    float sb  = fmaf(wb, wb, nb2);

    float aA = 0.0f, aB = 0.0f, aC = 0.0f;   // stream a accumulators
    float bA = 0.0f, bB = 0.0f, bC = 0.0f;   // stream b accumulators

#pragma unroll
    for (int j = 0; j < 32; ++j) {
        float wr  = W1[2 * j];
        float wn  = W1[2 * j + 1];
        float bj  = b1[j];
        float w2a = W2[j];
        float w2b = W2[32 + j];
        float w2c = W2[64 + j];

        float pa = fmaf(wr, wa, fmaf(wn, nna, bj));
        float pb = fmaf(wr, wb, fmaf(wn, nnb, bj));

        // table lookup: u = (pre - lo)/h, clamp, split int/frac
        float ua = fminf(fmaxf(fmaf(pa, TAB_INVH, TAB_BIAS), 0.0f), 255.0f);
        float ub = fminf(fmaxf(fmaf(pb, TAB_INVH, TAB_BIAS), 0.0f), 255.0f);
        float fia = floorf(ua);
        float fib = floorf(ub);
        float fa = ua - fia;
        float fb = ub - fib;
        float4 ca = tab[(int)fia];
        float4 cb = tab[(int)fib];

        float ga = fmaf(fmaf(fmaf(ca.w, fa, ca.z), fa, ca.y), fa, ca.x);
        float gb = fmaf(fmaf(fmaf(cb.w, fb, cb.z), fb, cb.y), fb, cb.x);
        // positive tail: gelu(x) == x to <1e-9 beyond 6.34
        ga = (pa >= 6.34f) ? pa : ga;
        gb = (pb >= 6.34f) ? pb : gb;

        aA = fmaf(w2a, ga, aA);   bA = fmaf(w2a, gb, bA);
        aB = fmaf(w2b, ga, aB);   bB = fmaf(w2b, gb, bB);
        aC = fmaf(w2c, ga, aC);   bC = fmaf(w2c, gb, bC);
    }

    float avA = aA + b2[0];
    float bvA = aB + b2[1];
    float cvA = aC + b2[2];
    float avB = bA + b2[0];
    float bvB = bB + b2[1];
    float cvB = bC + b2[2];

    float alpha_in = alpha_p[0];
    float lam = __builtin_amdgcn_rcpf(
        1.0f + __builtin_amdgcn_exp2f(-alpha_in * 1.44269504f));
    float oml = 1.0f - lam;

    // ---- epilogue stream a ----
    float qa  = fmaf(4.0f * wa, wa, -sa);
    float ala = fmaf(cvA, qa, fmaf(bvA + bvA, wa, avA));
    float bea = -(sa * fmaf(cvA + cvA, wa, bvA));
    float t2a = fmaf(ala * bea, wa + wa, fmaf(ala * ala, sa, bea * bea));
    float inva = __builtin_amdgcn_rsqf(fmaxf(t2a, 1e-16f));
    float laa = lam * ala * inva;
    float lba = lam * bea * inva;
    float sca = oml + laa;

    float4 ra0, ra1;
    ra0.x = fmaf(sca, A0.x, lba);
    ra0.y = sca * A0.y;  ra0.z = sca * A0.z;  ra0.w = sca * A0.w;
    ra1.x = sca * A1.x;  ra1.y = sca * A1.y;  ra1.z = sca * A1.z;  ra1.w = sca * A1.w;

    // ---- epilogue stream b ----
    float qb  = fmaf(4.0f * wb, wb, -sb);
    float alb = fmaf(cvB, qb, fmaf(bvB + bvB, wb, avB));
    float beb = -(sb * fmaf(cvB + cvB, wb, bvB));
    float t2b = fmaf(alb * beb, wb + wb, fmaf(alb * alb, sb, beb * beb));
    float invb = __builtin_amdgcn_rsqf(fmaxf(t2b, 1e-16f));
    float lab = lam * alb * invb;
    float lbb = lam * beb * invb;
    float scb = oml + lab;

    float4 rb0, rb1;
    rb0.x = fmaf(scb, B0.x, lbb);
    rb0.y = scb * B0.y;  rb0.z = scb * B0.z;  rb0.w = scb * B0.w;
    rb1.x = scb * B1.x;  rb1.y = scb * B1.y;  rb1.z = scb * B1.z;  rb1.w = scb * B1.w;

    float4* op = (float4*)out;
    op[2 * i0]     = ra0;
    op[2 * i0 + 1] = ra1;
    op[2 * i1]     = rb0;
    op[2 * i1 + 1] = rb1;
}

extern "C" void kernel_launch(void* const* d_in, const int* in_sizes, int n_in,
                              void* d_out, int out_size, void* d_ws, size_t ws_size,
                              hipStream_t stream) {
    const float* o     = (const float*)d_in[0];
    const float* W1    = (const float*)d_in[1];
    const float* b1    = (const float*)d_in[2];
    const float* W2    = (const float*)d_in[3];
    const float* b2    = (const float*)d_in[4];
    const float* alpha = (const float*)d_in[5];
    float* out = (float*)d_out;

    int n_oct = in_sizes[0] / 8;
    int half = n_oct >> 1;           // fixed shape: 16*4096*64 = 4194304, even
    int block = 256;
    int grid = (half + block - 1) / block;
    g2_ffn_kernel<<<grid, block, 0, stream>>>(o, W1, b1, W2, b2, alpha, out, half);
}